// Round 1
// baseline (452.851 us; speedup 1.0000x reference)
//
#include <hip/hip_runtime.h>
#include <math.h>

#define BB    32
#define HID   4544
#define NQKV  4672
#define NKT   71      // 4544 / 64 k-tiles
#define KSG   24      // k-slices (grid.y) for both GEMMs
#define KVCAP 2048

// ---------------------------------------------------------------------------
// Skinny GEMM partial: C_part[slice][32][N] += x[32][4544] @ W[4544][N]
// thread = one output column, 32 row-accumulators. Weights: coalesced dword
// loads (lane = col). x: wave-uniform indices -> compiler emits s_load
// (scalar pipe), so inner loop is pure v_fmac with SGPR operand.
// ---------------------------------------------------------------------------
__global__ __launch_bounds__(256) void gemm32_part(
    const float* __restrict__ x, const float* __restrict__ W,
    float* __restrict__ part, int N)
{
  int col   = blockIdx.x * 256 + threadIdx.x;
  int slice = blockIdx.y;
  bool act  = col < N;
  int cidx  = act ? col : 0;
  float acc[32];
#pragma unroll
  for (int r = 0; r < 32; ++r) acc[r] = 0.f;

  for (int t = slice; t < NKT; t += KSG) {
    int k0 = t * 64;
    const float* wp = W + (size_t)k0 * N + cidx;
    const float* xp = x + k0;
#pragma unroll
    for (int kk = 0; kk < 64; kk += 4) {
      float w0 = wp[(size_t)(kk + 0) * N];
      float w1 = wp[(size_t)(kk + 1) * N];
      float w2 = wp[(size_t)(kk + 2) * N];
      float w3 = wp[(size_t)(kk + 3) * N];
#pragma unroll
      for (int r = 0; r < 32; ++r) {
        const float* xr = xp + r * HID + kk;   // wave-uniform -> s_load
        float a = acc[r];
        a = fmaf(xr[0], w0, a);
        a = fmaf(xr[1], w1, a);
        a = fmaf(xr[2], w2, a);
        a = fmaf(xr[3], w3, a);
        acc[r] = a;
      }
    }
  }
  if (act) {
    float* pp = part + (size_t)slice * 32 * N + col;
#pragma unroll
    for (int r = 0; r < 32; ++r) pp[(size_t)r * N] = acc[r];
  }
}

// ---------------------------------------------------------------------------
// Reduce QKV partials + RoPE(q,k) + prescale q by 1/sqrt(64).
// unit layout per row: 2304 rope pairs (72 heads x 32 j) + 64 v columns.
// ---------------------------------------------------------------------------
__global__ __launch_bounds__(256) void qkv_fix(
    const float* __restrict__ part, float* __restrict__ qkvr,
    const int* __restrict__ plen)
{
  int u = blockIdx.x * 256 + threadIdx.x;   // 32 * 2368 = 75776 exact
  int r = u / 2368, t = u % 2368;
  int past = *plen;

  if (t < 2304) {
    int head = t >> 5, j = t & 31;
    int c0 = head * 64 + j;          // heads 0..70 = q, head 71 = k
    int c1 = c0 + 32;
    float a = 0.f, b = 0.f;
    for (int s = 0; s < KSG; ++s) {
      const float* p = part + ((size_t)s * 32 + r) * NQKV;
      a += p[c0];
      b += p[c1];
    }
    float invf = (float)pow(10000.0, -(double)j / 32.0);
    float fr   = (float)past * invf;           // f32 product like reference
    float cs = (float)cos((double)fr);
    float sn = (float)sin((double)fr);
    float o0 = a * cs - b * sn;                // [-x2, x1] rotate-half
    float o1 = b * cs + a * sn;
    if (head < 71) { o0 *= 0.125f; o1 *= 0.125f; }  // fold 1/sqrt(64) into q
    qkvr[(size_t)r * NQKV + c0] = o0;
    qkvr[(size_t)r * NQKV + c1] = o1;
  } else {
    int c = 4608 + (t - 2304);                 // v passthrough
    float a = 0.f;
    for (int s = 0; s < KSG; ++s) a += part[((size_t)s * 32 + r) * NQKV + c];
    qkvr[(size_t)r * NQKV + c] = a;
  }
}

// ---------------------------------------------------------------------------
// Flash-decode partial. wave = (batch b, 64-pos chunk, head half).
// K rows in VGPR (lane = pos), V^T in VGPR (lane = d, coalesced loads),
// q via wave-uniform s_loads. probs transposed through per-wave LDS row.
// Position `past` comes from qkvr (cache never written). partial = (m,l,o[64]).
// ---------------------------------------------------------------------------
__global__ __launch_bounds__(256) void attn_part_k(
    const float* __restrict__ qkvr, const float* __restrict__ kc,
    const float* __restrict__ vc,   const float* __restrict__ mask,
    float* __restrict__ part,       const int* __restrict__ plen)
{
  int b    = blockIdx.x;
  int cg   = blockIdx.y;            // 0..15
  int w    = threadIdx.x >> 6;      // wave 0..3
  int lane = threadIdx.x & 63;
  int chunk = cg * 2 + (w & 1);     // 0..31
  int h0 = (w >> 1) ? 36 : 0;
  int h1 = (w >> 1) ? 71 : 36;
  int past  = *plen;
  int kvlen = past + 1;
  int pos0  = chunk * 64;

  __shared__ float pls[4][64];

  if (pos0 >= kvlen) {              // empty chunk: neutral partials
    for (int h = h0; h < h1; ++h) {
      size_t base = (((size_t)b * 71 + h) * 32 + chunk) * 66;
      if (lane == 0) { part[base] = -__builtin_inff(); part[base + 1] = 0.f; }
      part[base + 2 + lane] = 0.f;
    }
    return;
  }

  int pos = pos0 + lane;
  bool valid = pos < kvlen;
  const float* krow = (pos == past)
      ? (qkvr + (size_t)b * NQKV + 4544)
      : (kc + ((size_t)b * KVCAP + pos) * 64);
  float4 ka[16];
#pragma unroll
  for (int j = 0; j < 16; ++j) ka[j] = *(const float4*)(krow + j * 4);

  float vv[64];                     // V^T: vv[p] = V[pos0+p][lane]
#pragma unroll
  for (int p = 0; p < 64; ++p) {
    int pp = pos0 + p;
    const float* vrow = (pp == past)
        ? (qkvr + (size_t)b * NQKV + 4608)
        : (vc + ((size_t)b * KVCAP + pp) * 64);
    vv[p] = vrow[lane];
  }
  float mk = valid ? mask[(size_t)b * KVCAP + pos] : 0.f;

  for (int h = h0; h < h1; ++h) {
    const float* qh = qkvr + (size_t)b * NQKV + h * 64;  // uniform -> s_load
    float s0 = 0.f, s1 = 0.f, s2 = 0.f, s3 = 0.f;
#pragma unroll
    for (int j = 0; j < 16; ++j) {
      s0 = fmaf(ka[j].x, qh[j * 4 + 0], s0);
      s1 = fmaf(ka[j].y, qh[j * 4 + 1], s1);
      s2 = fmaf(ka[j].z, qh[j * 4 + 2], s2);
      s3 = fmaf(ka[j].w, qh[j * 4 + 3], s3);
    }
    float s = (s0 + s1) + (s2 + s3) + mk;
    if (!valid) s = -__builtin_inff();

    float m = s;
#pragma unroll
    for (int off = 32; off; off >>= 1) m = fmaxf(m, __shfl_xor(m, off, 64));
    float p = valid ? __expf(s - m) : 0.f;
    float l = p;
#pragma unroll
    for (int off = 32; off; off >>= 1) l += __shfl_xor(l, off, 64);

    pls[w][lane] = p;               // same-wave transpose; compiler waits lgkmcnt
    float o0 = 0.f, o1 = 0.f, o2 = 0.f, o3 = 0.f;
#pragma unroll
    for (int j = 0; j < 16; ++j) {
      float4 pr = *(const float4*)&pls[w][j * 4];
      o0 = fmaf(pr.x, vv[j * 4 + 0], o0);
      o1 = fmaf(pr.y, vv[j * 4 + 1], o1);
      o2 = fmaf(pr.z, vv[j * 4 + 2], o2);
      o3 = fmaf(pr.w, vv[j * 4 + 3], o3);
    }
    float o = (o0 + o1) + (o2 + o3);

    size_t base = (((size_t)b * 71 + h) * 32 + chunk) * 66;
    if (lane == 0) { part[base] = m; part[base + 1] = l; }
    part[base + 2 + lane] = o;
  }
}

// ---------------------------------------------------------------------------
// Merge 32 chunk partials per (b,h); wave per head, lane = d.
// ---------------------------------------------------------------------------
__global__ __launch_bounds__(256) void attn_comb(
    const float* __restrict__ part, float* __restrict__ ctx)
{
  int u = blockIdx.x * 4 + (threadIdx.x >> 6);   // (b*71+h), 2272 exact
  int lane = threadIdx.x & 63;
  if (u >= BB * 71) return;
  float M = -__builtin_inff(), L = 0.f, O = 0.f;
  for (int c = 0; c < 32; ++c) {
    size_t base = ((size_t)u * 32 + c) * 66;
    float mc = part[base];
    float lc = part[base + 1];
    float oc = part[base + 2 + lane];
    float nm = fmaxf(M, mc);
    if (nm == -__builtin_inff()) continue;       // both empty
    float ea = __expf(M - nm);
    float eb = __expf(mc - nm);
    O = O * ea + oc * eb;
    L = L * ea + lc * eb;
    M = nm;
  }
  int bb = u / 71, h = u % 71;
  ctx[(size_t)bb * HID + h * 64 + lane] = O / L;
}

// ---------------------------------------------------------------------------
// Final reduce of dense partials -> out. part layout [s][32*4544] flat.
// ---------------------------------------------------------------------------
__global__ __launch_bounds__(256) void sum_reduce(
    const float* __restrict__ part, float* __restrict__ out)
{
  int u = blockIdx.x * 256 + threadIdx.x;        // 145408 exact
  float a = 0.f;
  for (int s = 0; s < KSG; ++s) a += part[(size_t)s * (32 * HID) + u];
  out[u] = a;
}

// ---------------------------------------------------------------------------
extern "C" void kernel_launch(void* const* d_in, const int* in_sizes, int n_in,
                              void* d_out, int out_size, void* d_ws, size_t ws_size,
                              hipStream_t stream)
{
  const float* x    = (const float*)d_in[0];
  const float* mask = (const float*)d_in[1];
  const float* wqkv = (const float*)d_in[2];
  const float* wd   = (const float*)d_in[3];
  const float* kc   = (const float*)d_in[4];
  const float* vc   = (const float*)d_in[5];
  const int*   pl   = (const int*)d_in[6];
  float* out = (float*)d_out;
  float* ws  = (float*)d_ws;

  // ws layout (floats):
  //  part: shared by {QKV partials 24x32x4672, attn partials 32x71x32x66,
  //                   dense partials 24x32x4544} -> 4,798,464 f
  //  qkvr: 149,504 f    ctx: 145,408 f    total ~20.4 MB
  float* part = ws;
  float* qkvr = ws + 4798464;
  float* ctx  = ws + 4947968;

  gemm32_part<<<dim3(19, KSG), 256, 0, stream>>>(x, wqkv, part, NQKV);
  qkv_fix    <<<296,           256, 0, stream>>>(part, qkvr, pl);
  attn_part_k<<<dim3(32, 16),  256, 0, stream>>>(qkvr, kc, vc, mask, part, pl);
  attn_comb  <<<568,           256, 0, stream>>>(part, ctx);
  gemm32_part<<<dim3(18, KSG), 256, 0, stream>>>(ctx, wd, part, HID);
  sum_reduce <<<568,           256, 0, stream>>>(part, out);
}

// Round 2
// 420.410 us; speedup vs baseline: 1.0772x; 1.0772x over previous
//
#include <hip/hip_runtime.h>
#include <math.h>

#define BB    32
#define HID   4544
#define NQKV  4672
#define NKT   71      // 4544 / 64 k-tiles
#define KVCAP 2048

// ---------------------------------------------------------------------------
// Skinny GEMM partial: part[slice][32][N] = x[32][4544(slice-subset)] @ W
// Block: 256 output cols x 32 rows, one 64-k tile at a time (t += KSG).
// Thread: 4 contiguous cols x 8 rows (lane=col-group, wave=row-group).
// x staged transposed in LDS, read as all-lane-broadcast ds_read_b128
// (in-order lgkmcnt, finely waitable -- avoids the s_load lgkmcnt(0) drain
// that serialized round 1). Weights: coalesced dwordx4 vector loads.
// ---------------------------------------------------------------------------
__global__ __launch_bounds__(256) void gemm32v2(
    const float* __restrict__ x, const float* __restrict__ W,
    float* __restrict__ part, int N, int KSG)
{
  __shared__ float xT[64 * 32];          // [k][r]
  int lane = threadIdx.x & 63;
  int w    = threadIdx.x >> 6;
  int r0   = w * 8;
  int c0   = blockIdx.x * 256 + lane * 4;
  bool act = c0 < N;                     // N % 4 == 0 for both GEMMs
  int cb   = act ? c0 : 0;
  int slice = blockIdx.y;

  float acc[8][4];
#pragma unroll
  for (int r = 0; r < 8; ++r)
#pragma unroll
    for (int j = 0; j < 4; ++j) acc[r][j] = 0.f;

  for (int t = slice; t < NKT; t += KSG) {
    int k0 = t * 64;
    __syncthreads();                     // protect previous tile's xT reads
    {
      int idx = threadIdx.x * 8;         // 256 threads x 8 floats = 2048
      int r = idx >> 6, kk = idx & 63;
      const float* xp = x + (size_t)r * HID + k0 + kk;
      float4 a = *(const float4*)xp;
      float4 b = *(const float4*)(xp + 4);
      xT[(kk + 0) * 32 + r] = a.x;
      xT[(kk + 1) * 32 + r] = a.y;
      xT[(kk + 2) * 32 + r] = a.z;
      xT[(kk + 3) * 32 + r] = a.w;
      xT[(kk + 4) * 32 + r] = b.x;
      xT[(kk + 5) * 32 + r] = b.y;
      xT[(kk + 6) * 32 + r] = b.z;
      xT[(kk + 7) * 32 + r] = b.w;
    }
    __syncthreads();

    const float* wp = W + (size_t)k0 * N + cb;

#define FMA_STEP(KK, WV)                                                  \
    {                                                                     \
      float4 xa = *(const float4*)&xT[(KK) * 32 + r0];                    \
      float4 xb = *(const float4*)&xT[(KK) * 32 + r0 + 4];                \
      acc[0][0] = fmaf(xa.x, WV.x, acc[0][0]);                            \
      acc[0][1] = fmaf(xa.x, WV.y, acc[0][1]);                            \
      acc[0][2] = fmaf(xa.x, WV.z, acc[0][2]);                            \
      acc[0][3] = fmaf(xa.x, WV.w, acc[0][3]);                            \
      acc[1][0] = fmaf(xa.y, WV.x, acc[1][0]);                            \
      acc[1][1] = fmaf(xa.y, WV.y, acc[1][1]);                            \
      acc[1][2] = fmaf(xa.y, WV.z, acc[1][2]);                            \
      acc[1][3] = fmaf(xa.y, WV.w, acc[1][3]);                            \
      acc[2][0] = fmaf(xa.z, WV.x, acc[2][0]);                            \
      acc[2][1] = fmaf(xa.z, WV.y, acc[2][1]);                            \
      acc[2][2] = fmaf(xa.z, WV.z, acc[2][2]);                            \
      acc[2][3] = fmaf(xa.z, WV.w, acc[2][3]);                            \
      acc[3][0] = fmaf(xa.w, WV.x, acc[3][0]);                            \
      acc[3][1] = fmaf(xa.w, WV.y, acc[3][1]);                            \
      acc[3][2] = fmaf(xa.w, WV.z, acc[3][2]);                            \
      acc[3][3] = fmaf(xa.w, WV.w, acc[3][3]);                            \
      acc[4][0] = fmaf(xb.x, WV.x, acc[4][0]);                            \
      acc[4][1] = fmaf(xb.x, WV.y, acc[4][1]);                            \
      acc[4][2] = fmaf(xb.x, WV.z, acc[4][2]);                            \
      acc[4][3] = fmaf(xb.x, WV.w, acc[4][3]);                            \
      acc[5][0] = fmaf(xb.y, WV.x, acc[5][0]);                            \
      acc[5][1] = fmaf(xb.y, WV.y, acc[5][1]);                            \
      acc[5][2] = fmaf(xb.y, WV.z, acc[5][2]);                            \
      acc[5][3] = fmaf(xb.y, WV.w, acc[5][3]);                            \
      acc[6][0] = fmaf(xb.z, WV.x, acc[6][0]);                            \
      acc[6][1] = fmaf(xb.z, WV.y, acc[6][1]);                            \
      acc[6][2] = fmaf(xb.z, WV.z, acc[6][2]);                            \
      acc[6][3] = fmaf(xb.z, WV.w, acc[6][3]);                            \
      acc[7][0] = fmaf(xb.w, WV.x, acc[7][0]);                            \
      acc[7][1] = fmaf(xb.w, WV.y, acc[7][1]);                            \
      acc[7][2] = fmaf(xb.w, WV.z, acc[7][2]);                            \
      acc[7][3] = fmaf(xb.w, WV.w, acc[7][3]);                            \
    }

#pragma unroll 4
    for (int kc = 0; kc < 16; ++kc) {
      int k = kc * 4;
      float4 w0 = *(const float4*)(wp + (size_t)(k + 0) * N);
      float4 w1 = *(const float4*)(wp + (size_t)(k + 1) * N);
      float4 w2 = *(const float4*)(wp + (size_t)(k + 2) * N);
      float4 w3 = *(const float4*)(wp + (size_t)(k + 3) * N);
      FMA_STEP(k + 0, w0)
      FMA_STEP(k + 1, w1)
      FMA_STEP(k + 2, w2)
      FMA_STEP(k + 3, w3)
    }
#undef FMA_STEP
  }

  if (act) {
#pragma unroll
    for (int r = 0; r < 8; ++r) {
      float4 v = make_float4(acc[r][0], acc[r][1], acc[r][2], acc[r][3]);
      *(float4*)&part[((size_t)slice * 32 + r0 + r) * N + c0] = v;
    }
  }
}

// ---------------------------------------------------------------------------
// Reduce QKV partials + RoPE(q,k) + prescale q by 1/sqrt(64).
// ---------------------------------------------------------------------------
__global__ __launch_bounds__(256) void qkv_fix(
    const float* __restrict__ part, float* __restrict__ qkvr,
    const int* __restrict__ plen, int KSG)
{
  int u = blockIdx.x * 256 + threadIdx.x;   // 32 * 2368 = 75776 exact
  int r = u / 2368, t = u % 2368;
  int past = *plen;

  if (t < 2304) {
    int head = t >> 5, j = t & 31;
    int c0 = head * 64 + j;          // heads 0..70 = q, head 71 = k
    int c1 = c0 + 32;
    float a = 0.f, b = 0.f;
    for (int s = 0; s < KSG; ++s) {
      const float* p = part + ((size_t)s * 32 + r) * NQKV;
      a += p[c0];
      b += p[c1];
    }
    float invf = (float)pow(10000.0, -(double)j / 32.0);
    float fr   = (float)past * invf;           // f32 product like reference
    float cs = (float)cos((double)fr);
    float sn = (float)sin((double)fr);
    float o0 = a * cs - b * sn;                // [-x2, x1] rotate-half
    float o1 = b * cs + a * sn;
    if (head < 71) { o0 *= 0.125f; o1 *= 0.125f; }  // fold 1/sqrt(64) into q
    qkvr[(size_t)r * NQKV + c0] = o0;
    qkvr[(size_t)r * NQKV + c1] = o1;
  } else {
    int c = 4608 + (t - 2304);                 // v passthrough
    float a = 0.f;
    for (int s = 0; s < KSG; ++s) a += part[((size_t)s * 32 + r) * NQKV + c];
    qkvr[(size_t)r * NQKV + c] = a;
  }
}

// ---------------------------------------------------------------------------
// Flash-decode partial. wave = (batch b, 64-pos chunk, head half).
// q staged in LDS (broadcast ds_read_b128 -- in-order waits, no s_load drain).
// K rows in VGPR (lane = pos), V^T in VGPR (lane = d, coalesced loads).
// probs transposed through per-wave LDS row. Caches never written; position
// `past` reads k/v from qkvr. partial = (m, l, o[64]).
// ---------------------------------------------------------------------------
__global__ __launch_bounds__(256) void attn_part_k(
    const float* __restrict__ qkvr, const float* __restrict__ kc,
    const float* __restrict__ vc,   const float* __restrict__ mask,
    float* __restrict__ part,       const int* __restrict__ plen)
{
  int b    = blockIdx.x;
  int cg   = blockIdx.y;            // 0..15
  int w    = threadIdx.x >> 6;      // wave 0..3
  int lane = threadIdx.x & 63;
  int chunk = cg * 2 + (w & 1);     // 0..31
  int h0 = (w >> 1) ? 36 : 0;
  int h1 = (w >> 1) ? 71 : 36;
  int past  = *plen;
  int kvlen = past + 1;
  int pos0  = chunk * 64;

  __shared__ float qs[HID / 1 / 71 * 71];    // placeholder avoided below
  // real LDS:
  __shared__ float qsh[4544];
  __shared__ float pls[4][64];

  // stage q for this batch (all 71 heads) -- every wave participates, then
  // one barrier (before any early-out, so no barrier divergence).
  for (int i = threadIdx.x; i < 4544; i += 256)
    qsh[i] = qkvr[(size_t)b * NQKV + i];
  __syncthreads();
  (void)qs;

  if (pos0 >= kvlen) {              // empty chunk: neutral partials
    for (int h = h0; h < h1; ++h) {
      size_t base = (((size_t)b * 71 + h) * 32 + chunk) * 66;
      if (lane == 0) { part[base] = -__builtin_inff(); part[base + 1] = 0.f; }
      part[base + 2 + lane] = 0.f;
    }
    return;
  }

  int pos = pos0 + lane;
  bool valid = pos < kvlen;
  const float* krow = (pos == past)
      ? (qkvr + (size_t)b * NQKV + 4544)
      : (kc + ((size_t)b * KVCAP + pos) * 64);
  float4 ka[16];
#pragma unroll
  for (int j = 0; j < 16; ++j) ka[j] = *(const float4*)(krow + j * 4);

  float vv[64];                     // V^T: vv[p] = V[pos0+p][lane]
#pragma unroll
  for (int p = 0; p < 64; ++p) {
    int pp = pos0 + p;
    const float* vrow = (pp == past)
        ? (qkvr + (size_t)b * NQKV + 4608)
        : (vc + ((size_t)b * KVCAP + pp) * 64);
    vv[p] = vrow[lane];
  }
  float mk = valid ? mask[(size_t)b * KVCAP + pos] : 0.f;

  for (int h = h0; h < h1; ++h) {
    float s0 = 0.f, s1 = 0.f, s2 = 0.f, s3 = 0.f;
#pragma unroll
    for (int j = 0; j < 16; ++j) {
      float4 qv = *(const float4*)&qsh[h * 64 + j * 4];   // LDS broadcast
      s0 = fmaf(ka[j].x, qv.x, s0);
      s1 = fmaf(ka[j].y, qv.y, s1);
      s2 = fmaf(ka[j].z, qv.z, s2);
      s3 = fmaf(ka[j].w, qv.w, s3);
    }
    float s = (s0 + s1) + (s2 + s3) + mk;
    if (!valid) s = -__builtin_inff();

    float m = s;
#pragma unroll
    for (int off = 32; off; off >>= 1) m = fmaxf(m, __shfl_xor(m, off, 64));
    float p = valid ? __expf(s - m) : 0.f;
    float l = p;
#pragma unroll
    for (int off = 32; off; off >>= 1) l += __shfl_xor(l, off, 64);

    pls[w][lane] = p;               // same-wave transpose (lgkmcnt-ordered)
    float o0 = 0.f, o1 = 0.f, o2 = 0.f, o3 = 0.f;
#pragma unroll
    for (int j = 0; j < 16; ++j) {
      float4 pr = *(const float4*)&pls[w][j * 4];
      o0 = fmaf(pr.x, vv[j * 4 + 0], o0);
      o1 = fmaf(pr.y, vv[j * 4 + 1], o1);
      o2 = fmaf(pr.z, vv[j * 4 + 2], o2);
      o3 = fmaf(pr.w, vv[j * 4 + 3], o3);
    }
    float o = (o0 + o1) + (o2 + o3);

    size_t base = (((size_t)b * 71 + h) * 32 + chunk) * 66;
    if (lane == 0) { part[base] = m; part[base + 1] = l; }
    part[base + 2 + lane] = o;
  }
}

// ---------------------------------------------------------------------------
// Merge 32 chunk partials per (b,h); wave per head, lane = d.
// ---------------------------------------------------------------------------
__global__ __launch_bounds__(256) void attn_comb(
    const float* __restrict__ part, float* __restrict__ ctx)
{
  int u = blockIdx.x * 4 + (threadIdx.x >> 6);   // (b*71+h), 2272 exact
  int lane = threadIdx.x & 63;
  if (u >= BB * 71) return;
  float M = -__builtin_inff(), L = 0.f, O = 0.f;
  for (int c = 0; c < 32; ++c) {
    size_t base = ((size_t)u * 32 + c) * 66;
    float mc = part[base];
    float lc = part[base + 1];
    float oc = part[base + 2 + lane];
    float nm = fmaxf(M, mc);
    if (nm == -__builtin_inff()) continue;       // both empty
    float ea = __expf(M - nm);
    float eb = __expf(mc - nm);
    O = O * ea + oc * eb;
    L = L * ea + lc * eb;
    M = nm;
  }
  int bb = u / 71, h = u % 71;
  ctx[(size_t)bb * HID + h * 64 + lane] = O / L;
}

// ---------------------------------------------------------------------------
// Final reduce of dense partials -> out.
// ---------------------------------------------------------------------------
__global__ __launch_bounds__(256) void sum_reduce(
    const float* __restrict__ part, float* __restrict__ out, int KSG)
{
  int u = blockIdx.x * 256 + threadIdx.x;        // 145408 exact
  float a = 0.f;
  for (int s = 0; s < KSG; ++s) a += part[(size_t)s * (32 * HID) + u];
  out[u] = a;
}

// ---------------------------------------------------------------------------
extern "C" void kernel_launch(void* const* d_in, const int* in_sizes, int n_in,
                              void* d_out, int out_size, void* d_ws, size_t ws_size,
                              hipStream_t stream)
{
  const float* x    = (const float*)d_in[0];
  const float* mask = (const float*)d_in[1];
  const float* wqkv = (const float*)d_in[2];
  const float* wd   = (const float*)d_in[3];
  const float* kc   = (const float*)d_in[4];
  const float* vc   = (const float*)d_in[5];
  const int*   pl   = (const int*)d_in[6];
  float* out = (float*)d_out;
  float* ws  = (float*)d_ws;

  // k-slice count: adaptive to workspace, capped (partial-reduce traffic
  // scales with KSG; parallelism needs KSG >= ~24).
  size_t wf = ws_size / 4;
  long avail = (long)wf - 294912;                 // minus qkvr + ctx
  long slots = avail / 149504;                    // 32*NQKV per slice
  int KSG = (int)(slots < 1 ? 1 : (slots > 36 ? 36 : slots));

  size_t partReg = (size_t)KSG * 149504;
  if (partReg < 4795392) partReg = 4795392;       // attn partials alias here
  float* part = ws;
  float* qkvr = ws + partReg;
  float* ctx  = qkvr + 149504;

  gemm32v2   <<<dim3(19, KSG), 256, 0, stream>>>(x, wqkv, part, NQKV, KSG);
  qkv_fix    <<<296,           256, 0, stream>>>(part, qkvr, pl, KSG);
  attn_part_k<<<dim3(32, 16),  256, 0, stream>>>(qkvr, kc, vc, mask, part, pl);
  attn_comb  <<<568,           256, 0, stream>>>(part, ctx);
  gemm32v2   <<<dim3(18, KSG), 256, 0, stream>>>(ctx, wd, part, HID, KSG);
  sum_reduce <<<568,           256, 0, stream>>>(part, out, KSG);
}

// Round 3
// 354.841 us; speedup vs baseline: 1.2762x; 1.1848x over previous
//
#include <hip/hip_runtime.h>
#include <math.h>

#define BB    32
#define HID   4544
#define NQKV  4672
#define NKT   71      // 4544 / 64 k-tiles
#define KVCAP 2048

// ---------------------------------------------------------------------------
// Skinny GEMM partial: part[slice][32][N] = x[32][k-slice] @ W
// One 64-k tile per block (KSG ~= NKT) -> ~1349 blocks, ~20 waves/CU.
// Thread: 4 cols x 8 rows. x staged transposed in LDS (conflict-free:
// lane->row so bank == lane%32), read as broadcast ds_read_b128.
// Weight loads: fully unrolled, explicit 2-deep register double buffer
// (8 dwordx4 in flight continuously -- no chunk-boundary vmcnt drains).
// ---------------------------------------------------------------------------
__global__ __launch_bounds__(256) void gemm32v3(
    const float* __restrict__ x, const float* __restrict__ W,
    float* __restrict__ part, int N, int KSG)
{
  __shared__ float xT[64 * 32];          // [k][r]
  int lane = threadIdx.x & 63;
  int w    = threadIdx.x >> 6;
  int r0   = w * 8;
  int c0   = blockIdx.x * 256 + lane * 4;
  bool act = c0 < N;                     // N % 4 == 0 for both GEMMs
  int cb   = act ? c0 : 0;
  int slice = blockIdx.y;

  float acc[8][4];
#pragma unroll
  for (int r = 0; r < 8; ++r)
#pragma unroll
    for (int j = 0; j < 4; ++j) acc[r][j] = 0.f;

  for (int t = slice; t < NKT; t += KSG) {
    int k0 = t * 64;
    __syncthreads();                     // protect previous tile's xT reads
    {
      int r  = threadIdx.x & 31;         // lane->row: LDS bank == r -> no conflict
      int kg = threadIdx.x >> 5;
      const float* xp = x + (size_t)r * HID + k0 + kg * 8;
      float4 a = *(const float4*)xp;
      float4 b = *(const float4*)(xp + 4);
      int kk = kg * 8;
      xT[(kk + 0) * 32 + r] = a.x;
      xT[(kk + 1) * 32 + r] = a.y;
      xT[(kk + 2) * 32 + r] = a.z;
      xT[(kk + 3) * 32 + r] = a.w;
      xT[(kk + 4) * 32 + r] = b.x;
      xT[(kk + 5) * 32 + r] = b.y;
      xT[(kk + 6) * 32 + r] = b.z;
      xT[(kk + 7) * 32 + r] = b.w;
    }
    __syncthreads();

    const float* wp = W + (size_t)k0 * N + cb;

#define FMA_STEP(KK, WV)                                                  \
    {                                                                     \
      float4 xa = *(const float4*)&xT[(KK) * 32 + r0];                    \
      float4 xb = *(const float4*)&xT[(KK) * 32 + r0 + 4];                \
      acc[0][0] = fmaf(xa.x, WV.x, acc[0][0]);                            \
      acc[0][1] = fmaf(xa.x, WV.y, acc[0][1]);                            \
      acc[0][2] = fmaf(xa.x, WV.z, acc[0][2]);                            \
      acc[0][3] = fmaf(xa.x, WV.w, acc[0][3]);                            \
      acc[1][0] = fmaf(xa.y, WV.x, acc[1][0]);                            \
      acc[1][1] = fmaf(xa.y, WV.y, acc[1][1]);                            \
      acc[1][2] = fmaf(xa.y, WV.z, acc[1][2]);                            \
      acc[1][3] = fmaf(xa.y, WV.w, acc[1][3]);                            \
      acc[2][0] = fmaf(xa.z, WV.x, acc[2][0]);                            \
      acc[2][1] = fmaf(xa.z, WV.y, acc[2][1]);                            \
      acc[2][2] = fmaf(xa.z, WV.z, acc[2][2]);                            \
      acc[2][3] = fmaf(xa.z, WV.w, acc[2][3]);                            \
      acc[3][0] = fmaf(xa.w, WV.x, acc[3][0]);                            \
      acc[3][1] = fmaf(xa.w, WV.y, acc[3][1]);                            \
      acc[3][2] = fmaf(xa.w, WV.z, acc[3][2]);                            \
      acc[3][3] = fmaf(xa.w, WV.w, acc[3][3]);                            \
      acc[4][0] = fmaf(xb.x, WV.x, acc[4][0]);                            \
      acc[4][1] = fmaf(xb.x, WV.y, acc[4][1]);                            \
      acc[4][2] = fmaf(xb.x, WV.z, acc[4][2]);                            \
      acc[4][3] = fmaf(xb.x, WV.w, acc[4][3]);                            \
      acc[5][0] = fmaf(xb.y, WV.x, acc[5][0]);                            \
      acc[5][1] = fmaf(xb.y, WV.y, acc[5][1]);                            \
      acc[5][2] = fmaf(xb.y, WV.z, acc[5][2]);                            \
      acc[5][3] = fmaf(xb.y, WV.w, acc[5][3]);                            \
      acc[6][0] = fmaf(xb.z, WV.x, acc[6][0]);                            \
      acc[6][1] = fmaf(xb.z, WV.y, acc[6][1]);                            \
      acc[6][2] = fmaf(xb.z, WV.z, acc[6][2]);                            \
      acc[6][3] = fmaf(xb.z, WV.w, acc[6][3]);                            \
      acc[7][0] = fmaf(xb.w, WV.x, acc[7][0]);                            \
      acc[7][1] = fmaf(xb.w, WV.y, acc[7][1]);                            \
      acc[7][2] = fmaf(xb.w, WV.z, acc[7][2]);                            \
      acc[7][3] = fmaf(xb.w, WV.w, acc[7][3]);                            \
    }

#define LOADW(B0, B1, B2, B3, KB)                                         \
    {                                                                     \
      B0 = *(const float4*)(wp + (size_t)((KB) + 0) * N);                 \
      B1 = *(const float4*)(wp + (size_t)((KB) + 1) * N);                 \
      B2 = *(const float4*)(wp + (size_t)((KB) + 2) * N);                 \
      B3 = *(const float4*)(wp + (size_t)((KB) + 3) * N);                 \
    }
#define FMA4(B0, B1, B2, B3, KB)                                          \
    { FMA_STEP((KB) + 0, B0) FMA_STEP((KB) + 1, B1)                       \
      FMA_STEP((KB) + 2, B2) FMA_STEP((KB) + 3, B3) }

    float4 a0, a1, a2, a3, b0, b1, b2, b3;
    LOADW(a0, a1, a2, a3, 0)
    LOADW(b0, b1, b2, b3, 4)
    FMA4 (a0, a1, a2, a3, 0)
    LOADW(a0, a1, a2, a3, 8)
    FMA4 (b0, b1, b2, b3, 4)
    LOADW(b0, b1, b2, b3, 12)
    FMA4 (a0, a1, a2, a3, 8)
    LOADW(a0, a1, a2, a3, 16)
    FMA4 (b0, b1, b2, b3, 12)
    LOADW(b0, b1, b2, b3, 20)
    FMA4 (a0, a1, a2, a3, 16)
    LOADW(a0, a1, a2, a3, 24)
    FMA4 (b0, b1, b2, b3, 20)
    LOADW(b0, b1, b2, b3, 28)
    FMA4 (a0, a1, a2, a3, 24)
    LOADW(a0, a1, a2, a3, 32)
    FMA4 (b0, b1, b2, b3, 28)
    LOADW(b0, b1, b2, b3, 36)
    FMA4 (a0, a1, a2, a3, 32)
    LOADW(a0, a1, a2, a3, 40)
    FMA4 (b0, b1, b2, b3, 36)
    LOADW(b0, b1, b2, b3, 44)
    FMA4 (a0, a1, a2, a3, 40)
    LOADW(a0, a1, a2, a3, 48)
    FMA4 (b0, b1, b2, b3, 44)
    LOADW(b0, b1, b2, b3, 52)
    FMA4 (a0, a1, a2, a3, 48)
    LOADW(a0, a1, a2, a3, 56)
    FMA4 (b0, b1, b2, b3, 52)
    LOADW(b0, b1, b2, b3, 60)
    FMA4 (a0, a1, a2, a3, 56)
    FMA4 (b0, b1, b2, b3, 60)
#undef FMA_STEP
#undef LOADW
#undef FMA4
  }

  if (act) {
#pragma unroll
    for (int r = 0; r < 8; ++r) {
      float4 v = make_float4(acc[r][0], acc[r][1], acc[r][2], acc[r][3]);
      *(float4*)&part[((size_t)slice * 32 + r0 + r) * N + c0] = v;
    }
  }
}

// ---------------------------------------------------------------------------
// Reduce QKV partials + RoPE(q,k) + prescale q by 1/sqrt(64).
// 4 independent accumulator streams -> 8 loads in flight (was a serial
// dependent-load chain over runtime KSG).
// ---------------------------------------------------------------------------
__global__ __launch_bounds__(256) void qkv_fix(
    const float* __restrict__ part, float* __restrict__ qkvr,
    const int* __restrict__ plen, int KSG)
{
  int u = blockIdx.x * 256 + threadIdx.x;   // 32 * 2368 = 75776 exact
  int r = u / 2368, t = u % 2368;
  int past = *plen;
  const size_t SS = (size_t)32 * NQKV;      // slice stride

  if (t < 2304) {
    int head = t >> 5, j = t & 31;
    int c0 = head * 64 + j;          // heads 0..70 = q, head 71 = k
    int c1 = c0 + 32;
    const float* p = part + (size_t)r * NQKV;
    float a0 = 0.f, a1 = 0.f, a2 = 0.f, a3 = 0.f;
    float b0 = 0.f, b1 = 0.f, b2 = 0.f, b3 = 0.f;
    int s = 0;
    for (; s + 4 <= KSG; s += 4) {
      const float* q0 = p + (size_t)(s + 0) * SS;
      const float* q1 = p + (size_t)(s + 1) * SS;
      const float* q2 = p + (size_t)(s + 2) * SS;
      const float* q3 = p + (size_t)(s + 3) * SS;
      a0 += q0[c0]; b0 += q0[c1];
      a1 += q1[c0]; b1 += q1[c1];
      a2 += q2[c0]; b2 += q2[c1];
      a3 += q3[c0]; b3 += q3[c1];
    }
    for (; s < KSG; ++s) { a0 += p[(size_t)s * SS + c0]; b0 += p[(size_t)s * SS + c1]; }
    float a = (a0 + a1) + (a2 + a3);
    float b = (b0 + b1) + (b2 + b3);
    float invf = (float)pow(10000.0, -(double)j / 32.0);
    float fr   = (float)past * invf;           // f32 product like reference
    float cs = (float)cos((double)fr);
    float sn = (float)sin((double)fr);
    float o0 = a * cs - b * sn;                // [-x2, x1] rotate-half
    float o1 = b * cs + a * sn;
    if (head < 71) { o0 *= 0.125f; o1 *= 0.125f; }  // fold 1/sqrt(64) into q
    qkvr[(size_t)r * NQKV + c0] = o0;
    qkvr[(size_t)r * NQKV + c1] = o1;
  } else {
    int c = 4608 + (t - 2304);                 // v passthrough
    const float* p = part + (size_t)r * NQKV + c;
    float a0 = 0.f, a1 = 0.f, a2 = 0.f, a3 = 0.f;
    int s = 0;
    for (; s + 4 <= KSG; s += 4) {
      a0 += p[(size_t)(s + 0) * SS];
      a1 += p[(size_t)(s + 1) * SS];
      a2 += p[(size_t)(s + 2) * SS];
      a3 += p[(size_t)(s + 3) * SS];
    }
    for (; s < KSG; ++s) a0 += p[(size_t)s * SS];
    qkvr[(size_t)r * NQKV + c] = (a0 + a1) + (a2 + a3);
  }
}

// ---------------------------------------------------------------------------
// Flash-decode partial. block = (batch b, 64-pos chunk); 4 waves split the
// 71 heads in quarters (18/18/18/17) -> 1024 blocks, short per-wave chains.
// q staged in LDS (broadcast ds_read_b128). K rows in VGPR (lane = pos),
// V^T in VGPR (lane = d). probs transposed through per-wave LDS row.
// Caches never written; position `past` reads k/v from qkvr.
// ---------------------------------------------------------------------------
__global__ __launch_bounds__(256) void attn_part_k(
    const float* __restrict__ qkvr, const float* __restrict__ kc,
    const float* __restrict__ vc,   const float* __restrict__ mask,
    float* __restrict__ part,       const int* __restrict__ plen)
{
  int b     = blockIdx.x;
  int chunk = blockIdx.y;           // 0..31
  int w     = threadIdx.x >> 6;     // wave 0..3
  int lane  = threadIdx.x & 63;
  int h0 = w * 18;
  int h1 = (w == 3) ? 71 : (h0 + 18);
  int past  = *plen;
  int kvlen = past + 1;
  int pos0  = chunk * 64;

  __shared__ float qsh[4544];
  __shared__ float pls[4][64];

  // stage q for this batch (all 71 heads), vectorized; barrier before any
  // early-out so no barrier divergence.
  for (int i = threadIdx.x; i < 1136; i += 256)
    ((float4*)qsh)[i] = ((const float4*)(qkvr + (size_t)b * NQKV))[i];
  __syncthreads();

  if (pos0 >= kvlen) {              // empty chunk: neutral partials
    for (int h = h0; h < h1; ++h) {
      size_t base = (((size_t)b * 71 + h) * 32 + chunk) * 66;
      if (lane == 0) { part[base] = -__builtin_inff(); part[base + 1] = 0.f; }
      part[base + 2 + lane] = 0.f;
    }
    return;
  }

  int pos = pos0 + lane;
  bool valid = pos < kvlen;
  const float* krow = (pos == past)
      ? (qkvr + (size_t)b * NQKV + 4544)
      : (kc + ((size_t)b * KVCAP + pos) * 64);
  float4 ka[16];
#pragma unroll
  for (int j = 0; j < 16; ++j) ka[j] = *(const float4*)(krow + j * 4);

  float vv[64];                     // V^T: vv[p] = V[pos0+p][lane]
#pragma unroll
  for (int p = 0; p < 64; ++p) {
    int pp = pos0 + p;
    const float* vrow = (pp == past)
        ? (qkvr + (size_t)b * NQKV + 4608)
        : (vc + ((size_t)b * KVCAP + pp) * 64);
    vv[p] = vrow[lane];
  }
  float mk = valid ? mask[(size_t)b * KVCAP + pos] : 0.f;

  for (int h = h0; h < h1; ++h) {
    float s0 = 0.f, s1 = 0.f, s2 = 0.f, s3 = 0.f;
#pragma unroll
    for (int j = 0; j < 16; ++j) {
      float4 qv = *(const float4*)&qsh[h * 64 + j * 4];   // LDS broadcast
      s0 = fmaf(ka[j].x, qv.x, s0);
      s1 = fmaf(ka[j].y, qv.y, s1);
      s2 = fmaf(ka[j].z, qv.z, s2);
      s3 = fmaf(ka[j].w, qv.w, s3);
    }
    float s = (s0 + s1) + (s2 + s3) + mk;
    if (!valid) s = -__builtin_inff();

    float m = s;
#pragma unroll
    for (int off = 32; off; off >>= 1) m = fmaxf(m, __shfl_xor(m, off, 64));
    float p = valid ? __expf(s - m) : 0.f;
    float l = p;
#pragma unroll
    for (int off = 32; off; off >>= 1) l += __shfl_xor(l, off, 64);

    pls[w][lane] = p;               // same-wave transpose (lgkmcnt-ordered)
    float o0 = 0.f, o1 = 0.f, o2 = 0.f, o3 = 0.f;
#pragma unroll
    for (int j = 0; j < 16; ++j) {
      float4 pr = *(const float4*)&pls[w][j * 4];
      o0 = fmaf(pr.x, vv[j * 4 + 0], o0);
      o1 = fmaf(pr.y, vv[j * 4 + 1], o1);
      o2 = fmaf(pr.z, vv[j * 4 + 2], o2);
      o3 = fmaf(pr.w, vv[j * 4 + 3], o3);
    }
    float o = (o0 + o1) + (o2 + o3);

    size_t base = (((size_t)b * 71 + h) * 32 + chunk) * 66;
    if (lane == 0) { part[base] = m; part[base + 1] = l; }
    part[base + 2 + lane] = o;
  }
}

// ---------------------------------------------------------------------------
// Merge 32 chunk partials per (b,h); wave per head, lane = d.
// ---------------------------------------------------------------------------
__global__ __launch_bounds__(256) void attn_comb(
    const float* __restrict__ part, float* __restrict__ ctx)
{
  int u = blockIdx.x * 4 + (threadIdx.x >> 6);   // (b*71+h), 2272 exact
  int lane = threadIdx.x & 63;
  if (u >= BB * 71) return;
  float M = -__builtin_inff(), L = 0.f, O = 0.f;
  for (int c = 0; c < 32; ++c) {
    size_t base = ((size_t)u * 32 + c) * 66;
    float mc = part[base];
    float lc = part[base + 1];
    float oc = part[base + 2 + lane];
    float nm = fmaxf(M, mc);
    if (nm == -__builtin_inff()) continue;       // both empty
    float ea = __expf(M - nm);
    float eb = __expf(mc - nm);
    O = O * ea + oc * eb;
    L = L * ea + lc * eb;
    M = nm;
  }
  int bb = u / 71, h = u % 71;
  ctx[(size_t)bb * HID + h * 64 + lane] = O / L;
}

// ---------------------------------------------------------------------------
// Final reduce of dense partials -> out. 4 independent streams.
// ---------------------------------------------------------------------------
__global__ __launch_bounds__(256) void sum_reduce(
    const float* __restrict__ part, float* __restrict__ out, int KSG)
{
  int u = blockIdx.x * 256 + threadIdx.x;        // 145408 exact
  const size_t SS = (size_t)32 * HID;
  const float* p = part + u;
  float a0 = 0.f, a1 = 0.f, a2 = 0.f, a3 = 0.f;
  int s = 0;
  for (; s + 4 <= KSG; s += 4) {
    a0 += p[(size_t)(s + 0) * SS];
    a1 += p[(size_t)(s + 1) * SS];
    a2 += p[(size_t)(s + 2) * SS];
    a3 += p[(size_t)(s + 3) * SS];
  }
  for (; s < KSG; ++s) a0 += p[(size_t)s * SS];
  out[u] = (a0 + a1) + (a2 + a3);
}

// ---------------------------------------------------------------------------
extern "C" void kernel_launch(void* const* d_in, const int* in_sizes, int n_in,
                              void* d_out, int out_size, void* d_ws, size_t ws_size,
                              hipStream_t stream)
{
  const float* x    = (const float*)d_in[0];
  const float* mask = (const float*)d_in[1];
  const float* wqkv = (const float*)d_in[2];
  const float* wd   = (const float*)d_in[3];
  const float* kc   = (const float*)d_in[4];
  const float* vc   = (const float*)d_in[5];
  const int*   pl   = (const int*)d_in[6];
  float* out = (float*)d_out;
  float* ws  = (float*)d_ws;

  // k-slice count: adaptive to workspace. One k-tile per block when it fits
  // (KSG = 71) -> max GEMM parallelism; reduce kernels handle any KSG.
  size_t wf = ws_size / 4;
  long avail = (long)wf - 294912;                 // minus qkvr + ctx
  long slots = avail / 149504;                    // 32*NQKV per slice
  int KSG = (int)(slots < 1 ? 1 : (slots > NKT ? NKT : slots));

  size_t partReg = (size_t)KSG * 149504;
  if (partReg < 4795392) partReg = 4795392;       // attn partials alias here
  float* part = ws;
  float* qkvr = ws + partReg;
  float* ctx  = qkvr + 149504;

  gemm32v3   <<<dim3(19, KSG), 256, 0, stream>>>(x, wqkv, part, NQKV, KSG);
  qkv_fix    <<<296,           256, 0, stream>>>(part, qkvr, pl, KSG);
  attn_part_k<<<dim3(32, 32),  256, 0, stream>>>(qkvr, kc, vc, mask, part, pl);
  attn_comb  <<<568,           256, 0, stream>>>(part, ctx);
  gemm32v3   <<<dim3(18, KSG), 256, 0, stream>>>(ctx, wd, part, HID, KSG);
  sum_reduce <<<568,           256, 0, stream>>>(part, out, KSG);
}